// Round 1
// baseline (165.525 us; speedup 1.0000x reference)
//
#include <hip/hip_runtime.h>

// CBOW negative-sampling loss.
// Inputs (setup_inputs order):
//   d_in[0] context   [B, C]  int32
//   d_in[1] target    [B]     int32
//   d_in[2] negatives [B, K]  int32
//   d_in[3] in_emb    [V, D]  f32
//   d_in[4] out_emb   [V, D]  f32
// Output: scalar f32 = -mean_b( log(sig(pos)+eps) + sum_k log(sig(-neg_k)+eps) )

#define VOCAB  100000
#define DIM    128
#define B_TOT  16384
#define CWIN   10
#define K_NEG  10
#define EPS_F  1e-9f

// One wave (64 lanes) per batch element; lane i owns dims {2i, 2i+1} (float2).
// 4 waves per 256-thread block -> grid of B/4 = 4096 blocks.

__global__ void zero_acc_kernel(float* acc) {
    if (threadIdx.x == 0) acc[0] = 0.0f;
}

__global__ __launch_bounds__(256) void cbow_loss_kernel(
    const int*   __restrict__ context,
    const int*   __restrict__ target,
    const int*   __restrict__ negatives,
    const float* __restrict__ in_emb,
    const float* __restrict__ out_emb,
    float*       __restrict__ acc)
{
    const int wave = threadIdx.x >> 6;
    const int lane = threadIdx.x & 63;
    const int b    = blockIdx.x * 4 + wave;   // grid is exactly B/4

    const float2* in2  = (const float2*)in_emb;
    const float2* out2 = (const float2*)out_emb;

    // ---- context mean (lane-partial, dims 2*lane and 2*lane+1) ----
    float2 cm = make_float2(0.0f, 0.0f);
#pragma unroll
    for (int c = 0; c < CWIN; ++c) {
        const int idx = context[b * CWIN + c];
        const float2 v = in2[(size_t)idx * (DIM / 2) + lane];
        cm.x += v.x; cm.y += v.y;
    }
    cm.x *= (1.0f / CWIN);
    cm.y *= (1.0f / CWIN);

    // ---- lane-partial scores: s[0]=pos, s[1..K]=neg ----
    float s[K_NEG + 1];
    {
        const int t = target[b];
        const float2 v = out2[(size_t)t * (DIM / 2) + lane];
        s[0] = cm.x * v.x + cm.y * v.y;
    }
#pragma unroll
    for (int k = 0; k < K_NEG; ++k) {
        const int idx = negatives[b * K_NEG + k];
        const float2 v = out2[(size_t)idx * (DIM / 2) + lane];
        s[k + 1] = cm.x * v.x + cm.y * v.y;
    }

    // ---- wave butterfly reductions (64 lanes) ----
#pragma unroll
    for (int j = 0; j <= K_NEG; ++j) {
        float x = s[j];
#pragma unroll
        for (int off = 32; off > 0; off >>= 1)
            x += __shfl_xor(x, off, 64);
        s[j] = x;
    }

    // ---- per-b loss (all lanes redundantly; lane 0's value used) ----
    float l = logf(1.0f / (1.0f + expf(-s[0])) + EPS_F);          // pos: log(sig(s)+eps)
#pragma unroll
    for (int k = 1; k <= K_NEG; ++k)
        l += logf(1.0f / (1.0f + expf(s[k])) + EPS_F);            // neg: log(sig(-s)+eps)

    // ---- block reduce (4 waves) -> 1 atomic per block ----
    __shared__ float part[4];
    if (lane == 0) part[wave] = l;
    __syncthreads();
    if (threadIdx.x == 0) {
        atomicAdd(acc, part[0] + part[1] + part[2] + part[3]);
    }
}

__global__ void finalize_kernel(const float* __restrict__ acc,
                                float* __restrict__ out) {
    if (threadIdx.x == 0) out[0] = -acc[0] * (1.0f / B_TOT);
}

extern "C" void kernel_launch(void* const* d_in, const int* in_sizes, int n_in,
                              void* d_out, int out_size, void* d_ws, size_t ws_size,
                              hipStream_t stream) {
    const int*   context   = (const int*)  d_in[0];
    const int*   target    = (const int*)  d_in[1];
    const int*   negatives = (const int*)  d_in[2];
    const float* in_emb    = (const float*)d_in[3];
    const float* out_emb   = (const float*)d_in[4];
    float*       out       = (float*)d_out;
    float*       acc       = (float*)d_ws;   // 4 bytes of scratch; re-poisoned each call

    zero_acc_kernel<<<1, 64, 0, stream>>>(acc);
    cbow_loss_kernel<<<B_TOT / 4, 256, 0, stream>>>(
        context, target, negatives, in_emb, out_emb, acc);
    finalize_kernel<<<1, 64, 0, stream>>>(acc, out);
}

// Round 2
// 134.122 us; speedup vs baseline: 1.2341x; 1.2341x over previous
//
#include <hip/hip_runtime.h>

// CBOW negative-sampling loss.
// Inputs (setup_inputs order):
//   d_in[0] context   [B, C]  int32
//   d_in[1] target    [B]     int32
//   d_in[2] negatives [B, K]  int32
//   d_in[3] in_emb    [V, D]  f32
//   d_in[4] out_emb   [V, D]  f32
// Output: scalar f32 = -mean_b( log(sig(pos)+eps) + sum_k log(sig(-neg_k)+eps) )
//
// R2 layout: half-wave (32 lanes) per batch element, float4 (16B) per lane
// -> one 512B row per half-wave load, butterfly reduce = 5 stages within 32
// lanes (no cross-32 shuffle). Per-block partial to d_ws (no atomics, no
// zero kernel). 2 kernels total.

#define VOCAB  100000
#define DIM    128
#define B_TOT  16384
#define CWIN   10
#define K_NEG  10
#define EPS_F  1e-9f

#define BPB    8            // batch elements per block (256 thr = 4 waves = 8 halves)
#define NBLK   (B_TOT / BPB)   // 2048

__global__ __launch_bounds__(256, 8) void cbow_loss_kernel(
    const int*   __restrict__ context,
    const int*   __restrict__ target,
    const int*   __restrict__ negatives,
    const float* __restrict__ in_emb,
    const float* __restrict__ out_emb,
    float*       __restrict__ partials)
{
    const int tid  = threadIdx.x;
    const int halfId = tid >> 5;          // 0..7 within block
    const int sub  = tid & 31;            // lane within half-wave
    const int b    = blockIdx.x * BPB + halfId;

    const float4* in4  = (const float4*)in_emb;
    const float4* out4 = (const float4*)out_emb;

    // ---- context mean: lane-partial over dims [4*sub, 4*sub+3] ----
    float4 cm = make_float4(0.f, 0.f, 0.f, 0.f);
#pragma unroll
    for (int c = 0; c < CWIN; ++c) {
        const int idx = context[b * CWIN + c];
        const float4 v = in4[(size_t)idx * (DIM / 4) + sub];
        cm.x += v.x; cm.y += v.y; cm.z += v.z; cm.w += v.w;
    }
    cm.x *= (1.0f / CWIN); cm.y *= (1.0f / CWIN);
    cm.z *= (1.0f / CWIN); cm.w *= (1.0f / CWIN);

    // ---- lane-partial scores: s[0]=pos, s[1..K]=neg ----
    float s[K_NEG + 1];
    {
        const int t = target[b];
        const float4 v = out4[(size_t)t * (DIM / 4) + sub];
        s[0] = cm.x * v.x + cm.y * v.y + cm.z * v.z + cm.w * v.w;
    }
#pragma unroll
    for (int k = 0; k < K_NEG; ++k) {
        const int idx = negatives[b * K_NEG + k];
        const float4 v = out4[(size_t)idx * (DIM / 4) + sub];
        s[k + 1] = cm.x * v.x + cm.y * v.y + cm.z * v.z + cm.w * v.w;
    }

    // ---- butterfly reduce within the 32-lane half (5 stages) ----
#pragma unroll
    for (int j = 0; j <= K_NEG; ++j) {
        float x = s[j];
#pragma unroll
        for (int off = 16; off > 0; off >>= 1)
            x += __shfl_xor(x, off, 64);   // offsets <32 stay within each half
        s[j] = x;
    }

    // ---- per-b loss (redundant across 32 lanes; lane sub==0 used) ----
    float l = __logf(1.0f / (1.0f + __expf(-s[0])) + EPS_F);       // pos
#pragma unroll
    for (int k = 1; k <= K_NEG; ++k)
        l += __logf(1.0f / (1.0f + __expf(s[k])) + EPS_F);         // neg

    // ---- block reduce (8 halves) -> one partial per block ----
    __shared__ float part[BPB];
    if (sub == 0) part[halfId] = l;
    __syncthreads();
    if (tid == 0) {
        float t = 0.f;
#pragma unroll
        for (int i = 0; i < BPB; ++i) t += part[i];
        partials[blockIdx.x] = t;
    }
}

__global__ __launch_bounds__(256) void finalize_kernel(
    const float* __restrict__ partials,   // NBLK floats
    float*       __restrict__ out)
{
    const int tid  = threadIdx.x;
    const int lane = tid & 63;
    const int wave = tid >> 6;

    float x = 0.f;
#pragma unroll
    for (int j = 0; j < NBLK / 256; ++j)
        x += partials[tid + 256 * j];

#pragma unroll
    for (int off = 32; off > 0; off >>= 1)
        x += __shfl_xor(x, off, 64);

    __shared__ float part[4];
    if (lane == 0) part[wave] = x;
    __syncthreads();
    if (tid == 0)
        out[0] = -(part[0] + part[1] + part[2] + part[3]) * (1.0f / B_TOT);
}

extern "C" void kernel_launch(void* const* d_in, const int* in_sizes, int n_in,
                              void* d_out, int out_size, void* d_ws, size_t ws_size,
                              hipStream_t stream) {
    const int*   context   = (const int*)  d_in[0];
    const int*   target    = (const int*)  d_in[1];
    const int*   negatives = (const int*)  d_in[2];
    const float* in_emb    = (const float*)d_in[3];
    const float* out_emb   = (const float*)d_in[4];
    float*       out       = (float*)d_out;
    float*       partials  = (float*)d_ws;   // NBLK floats; fully written each call

    cbow_loss_kernel<<<NBLK, 256, 0, stream>>>(
        context, target, negatives, in_emb, out_emb, partials);
    finalize_kernel<<<1, 256, 0, stream>>>(partials, out);
}

// Round 3
// 130.312 us; speedup vs baseline: 1.2702x; 1.0292x over previous
//
#include <hip/hip_runtime.h>

// CBOW negative-sampling loss.
// Inputs (setup_inputs order):
//   d_in[0] context   [B, C]  int32
//   d_in[1] target    [B]     int32
//   d_in[2] negatives [B, K]  int32
//   d_in[3] in_emb    [V, D]  f32
//   d_in[4] out_emb   [V, D]  f32
// Output: scalar f32 = -mean_b( log(sig(pos)+eps) + sum_k log(sig(-neg_k)+eps) )
//
// R3: half-wave (32 lanes) per b, float4/lane. All 21 indices of a half-wave
// fetched by ONE predicated lane-parallel load + __shfl broadcast; all 21
// row-gathers staged into registers (max MLP per wave, ~21 outstanding 512B
// loads). Per-b loss written directly to ws (no LDS/atomics in main kernel).

#define VOCAB  100000
#define DIM    128
#define B_TOT  16384
#define CWIN   10
#define K_NEG  10
#define EPS_F  1e-9f

#define BPB    8               // b's per 256-thread block (8 half-waves)
#define NBLK   (B_TOT / BPB)   // 2048 blocks

__global__ __launch_bounds__(256, 4) void cbow_loss_kernel(
    const int*   __restrict__ context,
    const int*   __restrict__ target,
    const int*   __restrict__ negatives,
    const float* __restrict__ in_emb,
    const float* __restrict__ out_emb,
    float*       __restrict__ per_b)       // B_TOT floats in ws
{
    const int tid    = threadIdx.x;
    const int halfId = tid >> 5;           // 0..7
    const int sub    = tid & 31;           // lane within half-wave
    const int b      = blockIdx.x * BPB + halfId;

    const float4* in4  = (const float4*)in_emb;
    const float4* out4 = (const float4*)out_emb;

    // ---- ONE predicated load fetches all 21 indices for this half-wave ----
    // lanes 0..9  -> context[b*10+sub]
    // lanes 10..19-> negatives[b*10+(sub-10)]
    // lane  20    -> target[b]
    int myIdx = 0;
    {
        const int* p  = target;
        int        off = b;
        if (sub < CWIN)                 { p = context;   off = b * CWIN + sub; }
        else if (sub < 2 * CWIN)        { p = negatives; off = b * K_NEG + (sub - CWIN); }
        if (sub <= 2 * CWIN) myIdx = p[off];
    }

    // ---- stage all 21 row-gathers into registers (max outstanding loads) ----
    float4 cr[CWIN];
#pragma unroll
    for (int c = 0; c < CWIN; ++c) {
        const int idx = __shfl(myIdx, c, 32);            // broadcast within half
        cr[c] = in4[(idx << 5) + sub];                   // idx*32 float4s, 32-bit off
    }
    float4 ov[K_NEG + 1];
#pragma unroll
    for (int k = 0; k <= K_NEG; ++k) {
        const int lanesrc = (k == 0) ? 2 * CWIN : (CWIN + k - 1);
        const int idx = __shfl(myIdx, lanesrc, 32);
        ov[k] = out4[(idx << 5) + sub];
    }

    // ---- context mean (lane-partial over dims 4*sub..4*sub+3) ----
    float4 cm = make_float4(0.f, 0.f, 0.f, 0.f);
#pragma unroll
    for (int c = 0; c < CWIN; ++c) {
        cm.x += cr[c].x; cm.y += cr[c].y; cm.z += cr[c].z; cm.w += cr[c].w;
    }
    cm.x *= (1.0f / CWIN); cm.y *= (1.0f / CWIN);
    cm.z *= (1.0f / CWIN); cm.w *= (1.0f / CWIN);

    // ---- lane-partial scores ----
    float s[K_NEG + 1];
#pragma unroll
    for (int k = 0; k <= K_NEG; ++k)
        s[k] = cm.x * ov[k].x + cm.y * ov[k].y + cm.z * ov[k].z + cm.w * ov[k].w;

    // ---- butterfly reduce within the 32-lane half (5 stages) ----
#pragma unroll
    for (int j = 0; j <= K_NEG; ++j) {
        float x = s[j];
#pragma unroll
        for (int off = 16; off > 0; off >>= 1)
            x += __shfl_xor(x, off, 64);   // offsets <32 stay within each half
        s[j] = x;
    }

    // ---- per-b loss ----
    float l = __logf(1.0f / (1.0f + __expf(-s[0])) + EPS_F);       // pos
#pragma unroll
    for (int k = 1; k <= K_NEG; ++k)
        l += __logf(1.0f / (1.0f + __expf(s[k])) + EPS_F);         // neg

    if (sub == 0) per_b[b] = l;
}

__global__ __launch_bounds__(256) void finalize_kernel(
    const float* __restrict__ per_b,      // B_TOT floats
    float*       __restrict__ out)
{
    const int tid  = threadIdx.x;
    const int lane = tid & 63;
    const int wave = tid >> 6;

    float x = 0.f;
#pragma unroll
    for (int j = 0; j < B_TOT / 256; ++j)
        x += per_b[tid + 256 * j];

#pragma unroll
    for (int off = 32; off > 0; off >>= 1)
        x += __shfl_xor(x, off, 64);

    __shared__ float part[4];
    if (lane == 0) part[wave] = x;
    __syncthreads();
    if (tid == 0)
        out[0] = -(part[0] + part[1] + part[2] + part[3]) * (1.0f / B_TOT);
}

extern "C" void kernel_launch(void* const* d_in, const int* in_sizes, int n_in,
                              void* d_out, int out_size, void* d_ws, size_t ws_size,
                              hipStream_t stream) {
    const int*   context   = (const int*)  d_in[0];
    const int*   target    = (const int*)  d_in[1];
    const int*   negatives = (const int*)  d_in[2];
    const float* in_emb    = (const float*)d_in[3];
    const float* out_emb   = (const float*)d_in[4];
    float*       out       = (float*)d_out;
    float*       per_b     = (float*)d_ws;   // B_TOT floats; fully written each call

    cbow_loss_kernel<<<NBLK, 256, 0, stream>>>(
        context, target, negatives, in_emb, out_emb, per_b);
    finalize_kernel<<<1, 256, 0, stream>>>(per_b, out);
}